// Round 3
// baseline (70066.382 us; speedup 1.0000x reference)
//
#include <hip/hip_runtime.h>

#define BATCH 256
#define SEQ   1024
#define HID   256
#define NU    4      // unit-slices (sibling blocks per batch-group)
#define UNITS 64     // hidden units per block (NU*UNITS == HID)
#define BB    4      // batch elements per block
#define NBG   64     // batch groups (NBG*BB == BATCH)
#define NKG   16     // k-groups inside a block
#define KPG   16     // k columns per k-group (NKG*KPG == HID)

// ---------- fast activations (fp32, ~2 ulp) ----------
__device__ __forceinline__ float tanh_fast(float x) {
    float e = __expf(2.0f * x);
    return 1.0f - 2.0f / (e + 1.0f);
}
__device__ __forceinline__ float sigmoid_fast(float x) {
    return 1.0f / (1.0f + __expf(-x));
}

// ---------- MLP ----------
template<int DIN, int DOUT, bool ACT>
__device__ __forceinline__ void dense(const float* __restrict__ w,
                                      const float* __restrict__ b,
                                      const float* hin, float* hout) {
    #pragma unroll
    for (int i = 0; i < DOUT; i++) {
        float a = b[i];
        #pragma unroll
        for (int j = 0; j < DIN; j++) a = fmaf(w[i * DIN + j], hin[j], a);
        hout[i] = ACT ? tanh_fast(a) : a;
    }
}

__global__ __launch_bounds__(256) void mlp_kernel(
    const float* __restrict__ x,
    const float* __restrict__ w1, const float* __restrict__ b1,
    const float* __restrict__ w2, const float* __restrict__ b2,
    const float* __restrict__ w3, const float* __restrict__ b3,
    const float* __restrict__ w4, const float* __restrict__ b4,
    const float* __restrict__ w5, const float* __restrict__ b5,
    const float* __restrict__ w6, const float* __restrict__ b6,
    const float* __restrict__ w7, const float* __restrict__ b7,
    float* __restrict__ cnn_out)
{
    int n = blockIdx.x * 256 + threadIdx.x;          // n = b*SEQ + s
    float h0[1] = { x[n] };
    float h1[16], h2[16], h3[12], h4[8], h5[4], h6[4], h7[1];
    dense<1, 16, true >(w1, b1, h0, h1);
    dense<16, 16, true >(w2, b2, h1, h2);
    dense<16, 12, true >(w3, b3, h2, h3);
    dense<12, 8, true >(w4, b4, h3, h4);
    dense<8, 4, true >(w5, b5, h4, h5);
    dense<4, 4, true >(w6, b6, h5, h6);
    dense<4, 1, false>(w7, b7, h6, h7);
    cnn_out[n] = h7[0];
}

// ---------- weight pack: wpack[k][j] = (wf, wi, wg, wo)[j][k], k=0..256 ----------
__global__ __launch_bounds__(256) void pack_kernel(
    const float* __restrict__ wf, const float* __restrict__ wi,
    const float* __restrict__ wg, const float* __restrict__ wo,
    float4* __restrict__ wpack)
{
    int j = threadIdx.x;
    int k = blockIdx.x;                              // 257 blocks
    int src = j * 257 + k;
    wpack[k * 256 + j] = make_float4(wf[src], wi[src], wg[src], wo[src]);
}

#define GATE_FMA(W, HV)                      \
    acc.x = fmaf((W).x, (HV), acc.x);        \
    acc.y = fmaf((W).y, (HV), acc.y);        \
    acc.z = fmaf((W).z, (HV), acc.z);        \
    acc.w = fmaf((W).w, (HV), acc.w);

// ---------- LSTM ----------
// Grid 256 = NU(4) unit-slices x NBG(64) batch-groups; bid = u*64 + bg so the
// 4 siblings of a group share bid%8 -> same XCD under round-robin dispatch
// (perf heuristic; correctness uses agent-scope atomics).
// Block: 1024 threads = NKG(16) k-groups x UNITS(64). Thread (kg,j) holds
// weights w[f,i,g,o][unit u*64+j][k in kg-slice] = 16 float4 in registers.
// Per step: partial gate sums -> LDS 16-way reduce (threads (b',j)) ->
// activations + state update -> 1KB h-slice exchange with 3 siblings via
// global memory, parity double-buffered, release/acquire flag sync.
__global__ __launch_bounds__(1024) void lstm_kernel(
    const float* __restrict__ xB,                    // [BATCH][SEQ] cnn features
    const float4* __restrict__ wpack,                // [257][256] (f,i,g,o)
    const float* __restrict__ bf, const float* __restrict__ bi,
    const float* __restrict__ bg_, const float* __restrict__ bo,
    const float* __restrict__ w_head, const float* __restrict__ b_head,
    float* __restrict__ logits,
    float* __restrict__ hglob,                       // [2][256 blocks][256] floats
    int* __restrict__ flags)                         // [256]
{
    __shared__ float4 partial[NKG][BB][UNITS];       // 64 KB
    __shared__ __align__(16) float hx_s[BB][HID];    // 4 KB
    __shared__ float xlds[BB * SEQ];                 // 16 KB

    const int bid = blockIdx.x;
    const int u   = bid >> 6;                        // 0..3 unit-slice
    const int bgp = bid & 63;                        // 0..63 batch-group
    const int tid = threadIdx.x;
    const int kg  = tid >> 6;                        // 0..15
    const int j   = tid & 63;                        // 0..63
    const int unit = u * UNITS + j;

    // register-resident weight slice: k rows 1+kg*16 .. 1+kg*16+15
    float4 wreg[KPG];
    #pragma unroll
    for (int i = 0; i < KPG; i++)
        wreg[i] = wpack[(1 + kg * KPG + i) * HID + unit];
    const float4 w0   = wpack[unit];                 // k=0 (x) column
    const float4 bias = make_float4(bf[unit], bi[unit], bg_[unit], bo[unit]);

    // stage this group's x: xlds[b'*SEQ + s]
    #pragma unroll
    for (int i = 0; i < BB; i++)
        xlds[i * 1024 + tid] = xB[(bgp * BB) * SEQ + i * 1024 + tid];
    ((float*)hx_s)[tid] = 0.0f;

    float cx = 0.0f, hj = 0.0f;
    const int b2 = tid >> 6;                         // phase-2 mapping (tid<256)
    int* const myflag = flags + bid;
    __syncthreads();

    for (int t = 0; t < SEQ; ++t) {
        // ---- phase 1: partial gate sums (all 1024 threads) ----
        #pragma unroll
        for (int bb = 0; bb < BB; ++bb) {
            float4 acc = make_float4(0.f, 0.f, 0.f, 0.f);
            const float4* h4 = (const float4*)&hx_s[bb][kg * KPG];
            #pragma unroll
            for (int q = 0; q < KPG / 4; ++q) {
                float4 h = h4[q];
                GATE_FMA(wreg[4 * q + 0], h.x);
                GATE_FMA(wreg[4 * q + 1], h.y);
                GATE_FMA(wreg[4 * q + 2], h.z);
                GATE_FMA(wreg[4 * q + 3], h.w);
            }
            partial[kg][bb][j] = acc;
        }
        __syncthreads();

        // ---- phase 2: reduce + activations + state (threads (b2,j), tid<256) ----
        float hnew = 0.0f;
        if (tid < 256) {
            float4 acc = partial[0][b2][j];
            #pragma unroll
            for (int g = 1; g < NKG; ++g) {
                float4 p = partial[g][b2][j];
                acc.x += p.x; acc.y += p.y; acc.z += p.z; acc.w += p.w;
            }
            float xt = xlds[b2 * 1024 + t];
            float pf = fmaf(w0.x, xt, acc.x + bias.x);
            float pi = fmaf(w0.y, xt, acc.y + bias.y);
            float pg = fmaf(w0.z, xt, acc.z + bias.z);
            float po = fmaf(w0.w, xt, acc.w + bias.w);
            float f  = sigmoid_fast(pf);
            float i  = sigmoid_fast(pi);
            float g  = tanh_fast(pg);
            float o  = sigmoid_fast(po);
            cx = fmaf(f, cx, i * g);
            hnew = o * tanh_fast(cx);
            hj = hnew;
            hx_s[b2][u * UNITS + j] = hnew;          // own slice direct to LDS
        }

        if (t < SEQ - 1) {
            // ---- phase 3: publish own slice (parity double buffer) ----
            float* dst = hglob + (t & 1) * (256 * 256) + bid * 256;
            if (tid < 256) dst[tid] = hnew;
            __threadfence();                         // device-scope release of data
            __syncthreads();                         // all writers fenced
            if (tid == 0)
                __hip_atomic_store(myflag, t + 1, __ATOMIC_RELEASE,
                                   __HIP_MEMORY_SCOPE_AGENT);
            // ---- spin for 3 siblings ----
            if (tid < NU - 1) {
                int su = (u + 1 + tid) & 3;
                int* sf = flags + su * NBG + bgp;
                while (__hip_atomic_load(sf, __ATOMIC_ACQUIRE,
                                         __HIP_MEMORY_SCOPE_AGENT) < t + 1)
                    __builtin_amdgcn_s_sleep(1);
            }
            __syncthreads();
            // ---- phase 4: read 3 sibling slices into LDS ----
            if (tid < 768) {
                int s  = tid >> 8;                   // 0..2
                int su = (u + 1 + s) & 3;
                int r  = tid & 255;                  // (b', j) = (r>>6, r&63)
                float v = hglob[(t & 1) * (256 * 256) + (su * NBG + bgp) * 256 + r];
                hx_s[r >> 6][su * UNITS + (r & 63)] = v;
            }
            __syncthreads();
        }
    }

    // ---- head: logits[b] = sum_j w_head[j]*h[j] + b_head (4 partial blocks) ----
    __syncthreads();                                 // reuse partial[] as scratch
    float* red = (float*)partial;
    if (tid < 256) red[tid] = w_head[unit] * hj;
    __syncthreads();
    #pragma unroll
    for (int off = 32; off > 0; off >>= 1) {
        if (tid < 256 && (tid & 63) < off) red[tid] += red[tid + off];
        __syncthreads();
    }
    if (tid < 256 && (tid & 63) == 0) {
        float sum = red[tid] + (u == 0 ? b_head[0] : 0.0f);
        atomicAdd(&logits[bgp * BB + (tid >> 6)], sum);
    }
}

extern "C" void kernel_launch(void* const* d_in, const int* in_sizes, int n_in,
                              void* d_out, int out_size, void* d_ws, size_t ws_size,
                              hipStream_t stream) {
    const float* x      = (const float*)d_in[0];
    const float* w1     = (const float*)d_in[1];
    const float* b1     = (const float*)d_in[2];
    const float* w2     = (const float*)d_in[3];
    const float* b2     = (const float*)d_in[4];
    const float* w3     = (const float*)d_in[5];
    const float* b3     = (const float*)d_in[6];
    const float* w4     = (const float*)d_in[7];
    const float* b4     = (const float*)d_in[8];
    const float* w5     = (const float*)d_in[9];
    const float* b5     = (const float*)d_in[10];
    const float* w6     = (const float*)d_in[11];
    const float* b6     = (const float*)d_in[12];
    const float* w7     = (const float*)d_in[13];
    const float* b7     = (const float*)d_in[14];
    const float* w_f    = (const float*)d_in[15];
    const float* b_f    = (const float*)d_in[16];
    const float* w_i    = (const float*)d_in[17];
    const float* b_i    = (const float*)d_in[18];
    const float* w_g    = (const float*)d_in[19];
    const float* b_g    = (const float*)d_in[20];
    const float* w_o    = (const float*)d_in[21];
    const float* b_o    = (const float*)d_in[22];
    const float* w_head = (const float*)d_in[23];
    const float* b_head = (const float*)d_in[24];

    float*  out    = (float*)d_out;                  // [0..262143] cnn_features, then logits
    float*  logits = out + BATCH * SEQ;

    char* ws = (char*)d_ws;
    float4* wpack = (float4*)ws;                     // 1,052,672 B
    float*  hglob = (float*)(ws + 1052672);          // 2*256*256*4 = 524,288 B
    int*    flags = (int*)(ws + 1052672 + 524288);   // 1 KB

    hipMemsetAsync(flags, 0, 256 * sizeof(int), stream);
    hipMemsetAsync(logits, 0, 256 * sizeof(float), stream);
    pack_kernel<<<257, 256, 0, stream>>>(w_f, w_i, w_g, w_o, wpack);
    mlp_kernel<<<(BATCH * SEQ) / 256, 256, 0, stream>>>(
        x, w1, b1, w2, b2, w3, b3, w4, b4, w5, b5, w6, b6, w7, b7, out);

    void* args[] = { (void*)&out, (void*)&wpack,
                     (void*)&b_f, (void*)&b_i, (void*)&b_g, (void*)&b_o,
                     (void*)&w_head, (void*)&b_head,
                     (void*)&logits, (void*)&hglob, (void*)&flags };
    hipLaunchCooperativeKernel((void*)lstm_kernel, dim3(256), dim3(1024),
                               args, 0, stream);
}

// Round 5
// 3031.853 us; speedup vs baseline: 23.1101x; 23.1101x over previous
//
#include <hip/hip_runtime.h>

#define BATCH 256
#define SEQ   1024
#define HID   256
#define NU    4      // unit-slices (sibling blocks per batch-group)
#define UNITS 64     // hidden units per block (NU*UNITS == HID)
#define BB    4      // batch elements per block
#define NBG   64     // batch groups (NBG*BB == BATCH)
#define NKG   16     // k-groups inside a block
#define KPG   16     // k columns per k-group (NKG*KPG == HID)

// ---------- fast activations (fp32, ~2 ulp) ----------
__device__ __forceinline__ float tanh_fast(float x) {
    float e = __expf(2.0f * x);
    return 1.0f - 2.0f / (e + 1.0f);
}
__device__ __forceinline__ float sigmoid_fast(float x) {
    return 1.0f / (1.0f + __expf(-x));
}

// ---------- MLP ----------
template<int DIN, int DOUT, bool ACT>
__device__ __forceinline__ void dense(const float* __restrict__ w,
                                      const float* __restrict__ b,
                                      const float* hin, float* hout) {
    #pragma unroll
    for (int i = 0; i < DOUT; i++) {
        float a = b[i];
        #pragma unroll
        for (int j = 0; j < DIN; j++) a = fmaf(w[i * DIN + j], hin[j], a);
        hout[i] = ACT ? tanh_fast(a) : a;
    }
}

__global__ __launch_bounds__(256) void mlp_kernel(
    const float* __restrict__ x,
    const float* __restrict__ w1, const float* __restrict__ b1,
    const float* __restrict__ w2, const float* __restrict__ b2,
    const float* __restrict__ w3, const float* __restrict__ b3,
    const float* __restrict__ w4, const float* __restrict__ b4,
    const float* __restrict__ w5, const float* __restrict__ b5,
    const float* __restrict__ w6, const float* __restrict__ b6,
    const float* __restrict__ w7, const float* __restrict__ b7,
    float* __restrict__ cnn_out)
{
    int n = blockIdx.x * 256 + threadIdx.x;          // n = b*SEQ + s
    float h0[1] = { x[n] };
    float h1[16], h2[16], h3[12], h4[8], h5[4], h6[4], h7[1];
    dense<1, 16, true >(w1, b1, h0, h1);
    dense<16, 16, true >(w2, b2, h1, h2);
    dense<16, 12, true >(w3, b3, h2, h3);
    dense<12, 8, true >(w4, b4, h3, h4);
    dense<8, 4, true >(w5, b5, h4, h5);
    dense<4, 4, true >(w6, b6, h5, h6);
    dense<4, 1, false>(w7, b7, h6, h7);
    cnn_out[n] = h7[0];
}

// ---------- weight pack: wpack[k][j] = (wf, wi, wg, wo)[j][k], k=0..256 ----------
__global__ __launch_bounds__(256) void pack_kernel(
    const float* __restrict__ wf, const float* __restrict__ wi,
    const float* __restrict__ wg, const float* __restrict__ wo,
    float4* __restrict__ wpack)
{
    int j = threadIdx.x;
    int k = blockIdx.x;                              // 257 blocks
    int src = j * 257 + k;
    wpack[k * 256 + j] = make_float4(wf[src], wi[src], wg[src], wo[src]);
}

#define GATE_FMA(W, HV)                      \
    acc.x = fmaf((W).x, (HV), acc.x);        \
    acc.y = fmaf((W).y, (HV), acc.y);        \
    acc.z = fmaf((W).z, (HV), acc.z);        \
    acc.w = fmaf((W).w, (HV), acc.w);

// ---------- LSTM ----------
// Grid 256 = NU(4) unit-slices x NBG(64) batch-groups (cooperative: 1 block/CU).
// Block: 1024 threads = NKG(16) k-groups x UNITS(64); thread (kg,j) holds a
// 16-column k-slice of the gate weights for unit u*64+j in registers
// (16 float4 = 64 VGPR; launch_bounds(1024,4) allows 128).
// Cross-block h-exchange per step: tagged 8-byte RELAXED SYSTEM-scope atomics
// ((t+1)<<32 | f32bits) -> fine-grained stores straight to IF$.
// NO fences, NO cache-maintenance ops (the R3 killer). Consumers poll their
// own slot until the tag matches. Parity double-buffer makes overwrite safe:
// producer rewrites slot[par] two steps later, ordered behind all siblings'
// par+1 publications, which are behind their par consumption.
__global__ __launch_bounds__(1024, 4) void lstm_kernel(
    const float* __restrict__ xB,                    // [BATCH][SEQ] cnn features
    const float4* __restrict__ wpack,                // [257][256] (f,i,g,o)
    const float* __restrict__ bf, const float* __restrict__ bi,
    const float* __restrict__ bg_, const float* __restrict__ bo,
    const float* __restrict__ w_head, const float* __restrict__ b_head,
    float* __restrict__ logits,
    unsigned long long* __restrict__ hglob)          // [2][256 blocks][256] u64
{
    __shared__ float4 partial[NKG][BB][UNITS];       // 64 KB
    __shared__ __align__(16) float hx_s[BB][HID];    // 4 KB
    __shared__ float xlds[BB * SEQ];                 // 16 KB

    const int bid = blockIdx.x;
    const int u   = bid >> 6;                        // 0..3 unit-slice
    const int bgp = bid & 63;                        // 0..63 batch-group
    const int tid = threadIdx.x;
    const int kg  = tid >> 6;                        // 0..15
    const int j   = tid & 63;                        // 0..63
    const int unit = u * UNITS + j;

    // register-resident weight slice: k rows 1+kg*16 .. 1+kg*16+15
    float4 wreg[KPG];
    #pragma unroll
    for (int i = 0; i < KPG; i++)
        wreg[i] = wpack[(1 + kg * KPG + i) * HID + unit];
    const float4 w0   = wpack[unit];                 // k=0 (x) column
    const float4 bias = make_float4(bf[unit], bi[unit], bg_[unit], bo[unit]);

    // stage this group's x: xlds[b'*SEQ + s]
    #pragma unroll
    for (int i = 0; i < BB; i++)
        xlds[i * 1024 + tid] = xB[(bgp * BB) * SEQ + i * 1024 + tid];
    ((float*)hx_s)[tid] = 0.0f;

    float cx = 0.0f, hj = 0.0f;
    const int b2 = tid >> 6;                         // phase-2 mapping (tid<256)
    __syncthreads();

    for (int t = 0; t < SEQ; ++t) {
        // ---- phase 1: partial gate sums (all 1024 threads) ----
        #pragma unroll
        for (int bb = 0; bb < BB; ++bb) {
            float4 acc = make_float4(0.f, 0.f, 0.f, 0.f);
            const float4* h4 = (const float4*)&hx_s[bb][kg * KPG];
            #pragma unroll
            for (int q = 0; q < KPG / 4; ++q) {
                float4 h = h4[q];
                GATE_FMA(wreg[4 * q + 0], h.x);
                GATE_FMA(wreg[4 * q + 1], h.y);
                GATE_FMA(wreg[4 * q + 2], h.z);
                GATE_FMA(wreg[4 * q + 3], h.w);
            }
            partial[kg][bb][j] = acc;
        }
        __syncthreads();

        // ---- phase 2: reduce + activations + state (tid<256: (b2, j)) ----
        float hnew = 0.0f;
        if (tid < 256) {
            float4 acc = partial[0][b2][j];
            #pragma unroll
            for (int g = 1; g < NKG; ++g) {
                float4 p = partial[g][b2][j];
                acc.x += p.x; acc.y += p.y; acc.z += p.z; acc.w += p.w;
            }
            float xt = xlds[b2 * 1024 + t];
            float pf = fmaf(w0.x, xt, acc.x + bias.x);
            float pi = fmaf(w0.y, xt, acc.y + bias.y);
            float pg = fmaf(w0.z, xt, acc.z + bias.z);
            float po = fmaf(w0.w, xt, acc.w + bias.w);
            float f  = sigmoid_fast(pf);
            float i  = sigmoid_fast(pi);
            float g  = tanh_fast(pg);
            float o  = sigmoid_fast(po);
            cx = fmaf(f, cx, i * g);
            hnew = o * tanh_fast(cx);
            hj = hnew;
        }

        if (t < SEQ - 1) {
            const int par = t & 1;
            // ---- publish own slice: tagged 8B fine-grained store (fire & forget) ----
            if (tid < 256) {
                unsigned long long pk =
                    ((unsigned long long)(unsigned)(t + 1) << 32) |
                    (unsigned long long)__float_as_uint(hnew);
                __hip_atomic_store(&hglob[(size_t)par * (256 * 256) + bid * 256 + tid],
                                   pk, __ATOMIC_RELAXED, __HIP_MEMORY_SCOPE_SYSTEM);
                hx_s[b2][u * UNITS + j] = hnew;      // own slice direct to LDS
            }
            asm volatile("" ::: "memory");           // pin store before polls
            // ---- poll the 3 sibling slices (tid<768, one value each) ----
            if (tid < 768) {
                const int s  = tid >> 8;             // 0..2
                const int su = (u + 1 + s) & 3;
                const int r  = tid & 255;            // (b', j') = (r>>6, r&63)
                const unsigned long long* p =
                    hglob + (size_t)par * (256 * 256) + (su * NBG + bgp) * 256 + r;
                unsigned long long v;
                do {
                    v = __hip_atomic_load(p, __ATOMIC_RELAXED,
                                          __HIP_MEMORY_SCOPE_SYSTEM);
                } while ((int)(v >> 32) != t + 1);
                hx_s[r >> 6][su * UNITS + (r & 63)] =
                    __uint_as_float((unsigned)(v & 0xffffffffull));
            }
            __syncthreads();                         // hx complete for next step
        } else {
            if (tid < 256) hx_s[b2][u * UNITS + j] = hnew;
        }
    }

    // ---- head: logits[b] = sum_j w_head[j]*h[j] + b_head (4 partial blocks) ----
    __syncthreads();                                 // reuse partial[] as scratch
    float* red = (float*)partial;
    if (tid < 256) red[tid] = w_head[unit] * hj;
    __syncthreads();
    #pragma unroll
    for (int off = 32; off > 0; off >>= 1) {
        if (tid < 256 && (tid & 63) < off) red[tid] += red[tid + off];
        __syncthreads();
    }
    if (tid < 256 && (tid & 63) == 0) {
        float sum = red[tid] + (u == 0 ? b_head[0] : 0.0f);
        atomicAdd(&logits[bgp * BB + (tid >> 6)], sum);
    }
}

extern "C" void kernel_launch(void* const* d_in, const int* in_sizes, int n_in,
                              void* d_out, int out_size, void* d_ws, size_t ws_size,
                              hipStream_t stream) {
    const float* x      = (const float*)d_in[0];
    const float* w1     = (const float*)d_in[1];
    const float* b1     = (const float*)d_in[2];
    const float* w2     = (const float*)d_in[3];
    const float* b2     = (const float*)d_in[4];
    const float* w3     = (const float*)d_in[5];
    const float* b3     = (const float*)d_in[6];
    const float* w4     = (const float*)d_in[7];
    const float* b4     = (const float*)d_in[8];
    const float* w5     = (const float*)d_in[9];
    const float* b5     = (const float*)d_in[10];
    const float* w6     = (const float*)d_in[11];
    const float* b6     = (const float*)d_in[12];
    const float* w7     = (const float*)d_in[13];
    const float* b7     = (const float*)d_in[14];
    const float* w_f    = (const float*)d_in[15];
    const float* b_f    = (const float*)d_in[16];
    const float* w_i    = (const float*)d_in[17];
    const float* b_i    = (const float*)d_in[18];
    const float* w_g    = (const float*)d_in[19];
    const float* b_g    = (const float*)d_in[20];
    const float* w_o    = (const float*)d_in[21];
    const float* b_o    = (const float*)d_in[22];
    const float* w_head = (const float*)d_in[23];
    const float* b_head = (const float*)d_in[24];

    float* out    = (float*)d_out;                   // [0..262143] cnn_features, then logits
    float* logits = out + BATCH * SEQ;

    char* ws = (char*)d_ws;
    float4* wpack = (float4*)ws;                     // 1,052,672 B
    unsigned long long* hglob =
        (unsigned long long*)(ws + 1052672);         // 2*256*256*8 = 1,048,576 B

    hipMemsetAsync(hglob, 0, 2 * 256 * 256 * sizeof(unsigned long long), stream);
    hipMemsetAsync(logits, 0, 256 * sizeof(float), stream);
    pack_kernel<<<257, 256, 0, stream>>>(w_f, w_i, w_g, w_o, wpack);
    mlp_kernel<<<(BATCH * SEQ) / 256, 256, 0, stream>>>(
        x, w1, b1, w2, b2, w3, b3, w4, b4, w5, b5, w6, b6, w7, b7, out);

    void* args[] = { (void*)&out, (void*)&wpack,
                     (void*)&b_f, (void*)&b_i, (void*)&b_g, (void*)&b_o,
                     (void*)&w_head, (void*)&b_head,
                     (void*)&logits, (void*)&hglob };
    hipLaunchCooperativeKernel((void*)lstm_kernel, dim3(256), dim3(1024),
                               args, 0, stream);
}